// Round 10
// baseline (606.936 us; speedup 1.0000x reference)
//
#include <hip/hip_runtime.h>
#include <math.h>

#define T_TOTAL 16384   // B*S
#define C_DIM   4096
#define E_DIM   64
#define K_TOP   8
#define S_SEQ   4096
#define B_BATCH 4
#define NKQ     8       // K splits
#define KQ_LEN  512     // channels per split
#define BK      32      // channels per LDS tile
#define NTILE   16      // KQ_LEN / BK
#define TOK_BLK 128     // tokens per block

// ---- pack W: wp2[c4][j*4+eg] = float4 of W[eg*16+j][4c4..+4] ----
__global__ void pack_w_kernel(const float* __restrict__ w,
                              float4* __restrict__ wp2) {
    int g = blockIdx.x * 256 + threadIdx.x;    // [0, 1024*64)
    int c4 = g >> 6, slot = g & 63;
    int e = (slot & 3) * 16 + (slot >> 2);     // eg*16 + j
    wp2[g] = *reinterpret_cast<const float4*>(w + (size_t)e * C_DIM + c4 * 4);
}

// ---- kernel 1: partial GEMV, 2D register tile, WAVE-PRIVATE LDS ----
// grid 1024: tg = b&127 (128 tokens), kq = b>>7 (512-ch split).
// Wave wv owns tokens [tg*128 + wv*32, +32) and stages ONLY those rows into
// its private LDS region -> zero barriers; waves free-run so stalls
// decorrelate across the 16 waves/CU. c4 loop left to the compiler to
// unroll/schedule (deep W-load lookahead). Layout/bank patterns, numerics
// chains (ascending channels, 256-ch flush), wp2 format: identical to r9.
__global__ __launch_bounds__(256, 4)
void gemv8_kernel(const float* __restrict__ x,
                  const float4* __restrict__ wp2,
                  float* __restrict__ part) {
    const int tid  = threadIdx.x;
    const int lane = tid & 63;
    const int wv   = tid >> 6;
    const int tl   = lane & 15;
    const int eg   = lane >> 4;
    const int tg   = blockIdx.x & 127;
    const int kq   = blockIdx.x >> 7;
    const int tok0 = tg * TOK_BLK;
    const int wtok0 = tok0 + wv * 32;          // wave's 32 tokens

    // wave-private double-buffered x tiles; pad 8->9 slots (2-way read, free)
    __shared__ float4 xs[4][2][32][9];         // 36864 B

    // staging map: lane -> local rows {row8, row8+8, +16, +24}, slot ss
    const int row8 = lane >> 3;                // 0..7
    const int ss   = lane & 7;                 // 0..7
    const float* xsrc = x + (size_t)(wtok0 + row8) * C_DIM + kq * KQ_LEN + ss * 4;

    float4 xf0, xf1, xf2, xf3;
    // prologue: tile 0 -> regs -> private LDS buf 0
    xf0 = *reinterpret_cast<const float4*>(xsrc);
    xf1 = *reinterpret_cast<const float4*>(xsrc + 8 * C_DIM);
    xf2 = *reinterpret_cast<const float4*>(xsrc + 16 * C_DIM);
    xf3 = *reinterpret_cast<const float4*>(xsrc + 24 * C_DIM);
    xs[wv][0][row8][ss]      = xf0;
    xs[wv][0][row8 + 8][ss]  = xf1;
    xs[wv][0][row8 + 16][ss] = xf2;
    xs[wv][0][row8 + 24][ss] = xf3;

    float accO[2][16], accI[2][16];
#pragma unroll
    for (int j = 0; j < 16; ++j) {
        accO[0][j] = 0.0f; accO[1][j] = 0.0f;
        accI[0][j] = 0.0f; accI[1][j] = 0.0f;
    }

#pragma unroll 1
    for (int t = 0; t < NTILE; ++t) {
        if (t + 1 < NTILE) {                   // prefetch next tile into regs
            const float* xn = xsrc + (t + 1) * BK;
            xf0 = *reinterpret_cast<const float4*>(xn);
            xf1 = *reinterpret_cast<const float4*>(xn + 8 * C_DIM);
            xf2 = *reinterpret_cast<const float4*>(xn + 16 * C_DIM);
            xf3 = *reinterpret_cast<const float4*>(xn + 24 * C_DIM);
        }
        const int cur = t & 1;

        // compute: compiler free to unroll the 8 c4 steps & pipeline W loads
        for (int c4 = 0; c4 < 8; ++c4) {
            const float4 xv0 = xs[wv][cur][tl][c4];
            const float4 xv1 = xs[wv][cur][tl + 16][c4];
            const float4* wrow =
                wp2 + (((size_t)(kq * (KQ_LEN / 4) + t * 8 + c4)) << 6) + eg;
#pragma unroll
            for (int jh = 0; jh < 4; ++jh) {
                float4 w4[4];
#pragma unroll
                for (int jj = 0; jj < 4; ++jj)
                    w4[jj] = wrow[(jh * 4 + jj) * 4];   // one 64B line/instr
#pragma unroll
                for (int jj = 0; jj < 4; ++jj) {
                    const int j = jh * 4 + jj;
                    float a0 = accI[0][j], a1 = accI[1][j];
                    a0 = fmaf(xv0.x, w4[jj].x, a0);
                    a0 = fmaf(xv0.y, w4[jj].y, a0);
                    a0 = fmaf(xv0.z, w4[jj].z, a0);
                    a0 = fmaf(xv0.w, w4[jj].w, a0);
                    a1 = fmaf(xv1.x, w4[jj].x, a1);
                    a1 = fmaf(xv1.y, w4[jj].y, a1);
                    a1 = fmaf(xv1.z, w4[jj].z, a1);
                    a1 = fmaf(xv1.w, w4[jj].w, a1);
                    accI[0][j] = a0; accI[1][j] = a1;
                }
            }
        }
        if ((t & 7) == 7) {                    // flush every 256 channels
#pragma unroll
            for (int j = 0; j < 16; ++j) {
                accO[0][j] += accI[0][j]; accI[0][j] = 0.0f;
                accO[1][j] += accI[1][j]; accI[1][j] = 0.0f;
            }
        }
        if (t + 1 < NTILE) {                   // commit prefetch to other buf
            const int nxt = cur ^ 1;
            xs[wv][nxt][row8][ss]      = xf0;
            xs[wv][nxt][row8 + 8][ss]  = xf1;
            xs[wv][nxt][row8 + 16][ss] = xf2;
            xs[wv][nxt][row8 + 24][ss] = xf3;
        }
        // NO barrier: regions are wave-private
    }

    // store partials: part[kq][tok][e]; 16 consecutive experts per lane
#pragma unroll
    for (int r = 0; r < 2; ++r) {
        float* pb = part + ((size_t)kq * T_TOTAL + wtok0 + tl + 16 * r)
                            * E_DIM + eg * 16;
#pragma unroll
        for (int q = 0; q < 4; ++q)
            *reinterpret_cast<float4*>(pb + 4 * q) =
                make_float4(accO[r][4 * q], accO[r][4 * q + 1],
                            accO[r][4 * q + 2], accO[r][4 * q + 3]);
    }
}

// ---- kernel 2: reduce 8 splits + sigmoid + top-8 + f/p partials ----
__global__ __launch_bounds__(256, 4)
void topk_kernel(const float* __restrict__ part,
                 const float* __restrict__ expert_bias,
                 float* __restrict__ out,
                 float* __restrict__ facc,
                 float* __restrict__ pacc) {
    const int lane = threadIdx.x & 63;
    const int wv   = threadIdx.x >> 6;
    const int tok0 = blockIdx.x * 64;

    __shared__ float slog[64][65];

    const int tt  = lane >> 2;
    const int s   = lane & 3;
    const int tl  = wv * 16 + tt;          // token-in-block
    const int tok = tok0 + tl;

    float4 sum4[4];
#pragma unroll
    for (int i = 0; i < 4; ++i) sum4[i] = make_float4(0.f, 0.f, 0.f, 0.f);
#pragma unroll
    for (int kq = 0; kq < NKQ; ++kq) {     // serial split sum (deterministic)
        const float4* pp = reinterpret_cast<const float4*>(
            part + ((size_t)kq * T_TOTAL + tok) * E_DIM + 16 * s);
#pragma unroll
        for (int i = 0; i < 4; ++i) {
            float4 v = pp[i];
            sum4[i].x += v.x; sum4[i].y += v.y;
            sum4[i].z += v.z; sum4[i].w += v.w;
        }
    }
#pragma unroll
    for (int i = 0; i < 4; ++i) {
        slog[tl][16 * s + 4 * i + 0] = sum4[i].x;
        slog[tl][16 * s + 4 * i + 1] = sum4[i].y;
        slog[tl][16 * s + 4 * i + 2] = sum4[i].z;
        slog[tl][16 * s + 4 * i + 3] = sum4[i].w;
    }
    __syncthreads();

    // ---- phase B: lane = expert; wave wv handles tokens wv*16 .. wv*16+15
    const float be = expert_bias[lane];
    const int   b  = tok0 / S_SEQ;         // uniform per block
    float f_local = 0.0f, p_local = 0.0f;

    for (int m = 0; m < 16; ++m) {
        const int tl2 = wv * 16 + m;
        const int tk  = tok0 + tl2;
        const float logit = slog[tl2][lane];
        const float sc = 1.0f / (1.0f + expf(-logit));   // sigmoid
        float ssum = sc;
#pragma unroll
        for (int off = 32; off >= 1; off >>= 1) ssum += __shfl_xor(ssum, off, 64);
        p_local += sc / (ssum + 1e-10f);

        // top-8 over biased logits (descending, lowest-index tie-break)
        float v = logit + be;
        float wsum = 0.0f, my_w = 0.0f;
        int   my_i = 0;
#pragma unroll
        for (int k = 0; k < K_TOP; ++k) {
            float rv = v;
            int   ri = lane;
#pragma unroll
            for (int off = 32; off >= 1; off >>= 1) {
                float ov = __shfl_xor(rv, off, 64);
                int   oi = __shfl_xor(ri, off, 64);
                if (ov > rv || (ov == rv && oi < ri)) { rv = ov; ri = oi; }
            }
            float wsc = __shfl(sc, ri, 64);   // winner's score (uniform)
            wsum += wsc;
            if (lane == k)  { my_i = ri; my_w = wsc; }
            if (lane == ri) { v = -INFINITY; f_local += 1.0f; }
        }
        if (lane < K_TOP) {
            out[(size_t)tk * K_TOP + lane] = (float)my_i;
            out[(size_t)T_TOTAL * K_TOP + (size_t)tk * K_TOP + lane] =
                my_w / (wsum + 1e-10f);
        }
    }

    atomicAdd(&facc[b * E_DIM + lane], f_local);
    atomicAdd(&pacc[b * E_DIM + lane], p_local);
}

// ---- tiny loss reduction: 4x64 f*p -> scalar ----
__global__ void loss_kernel(const float* __restrict__ facc,
                            const float* __restrict__ pacc,
                            float* __restrict__ out_loss) {
    const int tid = threadIdx.x;                 // 256 threads = B*E
    float f = facc[tid] * (1.0f / ((float)K_TOP * (float)S_SEQ));
    float p = pacc[tid] * (1.0f / (float)S_SEQ);
    float v = f * p;
#pragma unroll
    for (int off = 32; off >= 1; off >>= 1) v += __shfl_xor(v, off, 64);
    __shared__ float sred[4];
    if ((tid & 63) == 0) sred[tid >> 6] = v;
    __syncthreads();
    if (tid == 0) {
        float tot = sred[0] + sred[1] + sred[2] + sred[3];
        out_loss[0] = 0.001f * tot / (float)B_BATCH;
    }
}

extern "C" void kernel_launch(void* const* d_in, const int* in_sizes, int n_in,
                              void* d_out, int out_size, void* d_ws, size_t ws_size,
                              hipStream_t stream) {
    const float* x    = (const float*)d_in[0];   // [4,4096,4096] f32
    const float* w    = (const float*)d_in[1];   // [64,4096] f32
    const float* bias = (const float*)d_in[2];   // [64] f32
    float* out = (float*)d_out;                  // [131072 idx][131072 w][1 loss]

    float*  facc = (float*)d_ws;                 // 256 floats
    float*  pacc = facc + B_BATCH * E_DIM;       // 256 floats
    float4* wp2  = (float4*)((char*)d_ws + 4096);              // 1 MB packed W
    float*  part = (float*)((char*)d_ws + 4096 + (1 << 20));   // 32 MB partials

    // zero the f/p accumulators every call (atomics accumulate)
    hipMemsetAsync(d_ws, 0, 2048, stream);

    pack_w_kernel<<<256, 256, 0, stream>>>(w, wp2);

    gemv8_kernel<<<TOK_BLK * NKQ, 256, 0, stream>>>(x, wp2, part);

    topk_kernel<<<T_TOTAL / 64, 256, 0, stream>>>(part, bias, out, facc, pacc);

    loss_kernel<<<1, 256, 0, stream>>>(facc, pacc, out + 2 * (size_t)T_TOTAL * K_TOP);
}

// Round 11
// 562.934 us; speedup vs baseline: 1.0782x; 1.0782x over previous
//
#include <hip/hip_runtime.h>
#include <math.h>

#define T_TOTAL 16384   // B*S
#define C_DIM   4096
#define E_DIM   64
#define K_TOP   8
#define S_SEQ   4096
#define B_BATCH 4
#define NKQ     8       // K splits
#define KQ_LEN  512     // channels per split
#define BK      16      // channels per tile
#define NTILE   32      // KQ_LEN / BK

// ---- pack W: wp3[gt*256 + eh*128 + c4*32 + e2] = float4(W[eh*32+e2][(gt*4+c4)*4..]) ----
// gemv lane e2 then loads its 8 tile-float4s at stride 32 -> 512B coalesced/instr.
__global__ void pack_w_kernel(const float* __restrict__ w,
                              float4* __restrict__ wp3) {
    int g  = blockIdx.x * 256 + threadIdx.x;   // 0..65535
    int e2 = g & 31, c4 = (g >> 5) & 3, eh = (g >> 7) & 1, gt = g >> 8;
    int e   = eh * 32 + e2;
    int c4g = gt * 4 + c4;
    wp3[g] = *reinterpret_cast<const float4*>(w + (size_t)e * C_DIM + (size_t)c4g * 4);
}

// ---- kernel 1: partial GEMV — W stationary in VGPRs, x via LDS broadcast ----
// grid 1024: tgb = b&127 (128-token group), kq = b>>7 (512-ch split).
// Wave wv owns tokens [tgb*128 + wv*32, +32), wave-private LDS x-tile, NO
// barriers. lane = (tg2 = lane>>5: token half, e2 = lane&31: expert pair
// {e2, e2+32}). Per BK=16 tile: 8 W float4 -> regs (once, bounded), 64
// ds_read_b128 same-addr broadcasts (bank-free), 512 fma-instr.
// Numerics: ascending-channel chains, accI flushed every 256 ch (16 tiles),
// kq splits summed ascending in topk — identical grouping to r9 (absmax=0).
__global__ __launch_bounds__(256, 4)
void gemv_kernel(const float* __restrict__ x,
                 const float4* __restrict__ wp3,
                 float* __restrict__ part) {
    const int tid   = threadIdx.x;
    const int lane  = tid & 63;
    const int wv    = tid >> 6;
    const int e2    = lane & 31;
    const int tg2   = lane >> 5;
    const int tgb   = blockIdx.x & 127;
    const int kq    = blockIdx.x >> 7;
    const int wtok0 = tgb * 128 + wv * 32;      // wave's 32 tokens

    // wave-private double-buffered x tile: 32 rows x 20 floats (80B pad -> 8-way max on writes)
    __shared__ float xs[4][2][32 * 20];         // 20480 B

    // staging map: lane -> (row = lane>>1, half = lane&1), 2 float4 = 32B/row-half
    const int srow  = lane >> 1;
    const int shalf = lane & 1;
    const float* xsrc = x + (size_t)(wtok0 + srow) * C_DIM + kq * KQ_LEN + shalf * 8;

    // prologue: tile 0 -> regs -> LDS buf 0
    {
        float4 a = *reinterpret_cast<const float4*>(xsrc);
        float4 b = *reinterpret_cast<const float4*>(xsrc + 4);
        float* wd = &xs[wv][0][srow * 20 + shalf * 8];
        *reinterpret_cast<float4*>(wd)     = a;
        *reinterpret_cast<float4*>(wd + 4) = b;
    }

    float accI[2][16], accO[2][16];
#pragma unroll
    for (int t = 0; t < 16; ++t) {
        accI[0][t] = 0.0f; accI[1][t] = 0.0f;
        accO[0][t] = 0.0f; accO[1][t] = 0.0f;
    }

#pragma unroll 1
    for (int t = 0; t < NTILE; ++t) {
        const int cur = t & 1;

        // W tile: experts {e2, e2+32} x 16 ch -> 8 float4 regs (bounded)
        const float4* wt = wp3 + (size_t)(kq * NTILE + t) * 256 + e2;
        float4 wA[4], wB[4];
#pragma unroll
        for (int c = 0; c < 4; ++c) { wA[c] = wt[c * 32]; wB[c] = wt[128 + c * 32]; }

        // prefetch next x tile into regs (2 loads in flight across compute)
        float4 xf0, xf1;
        if (t + 1 < NTILE) {
            const float* xn = xsrc + (t + 1) * BK;
            xf0 = *reinterpret_cast<const float4*>(xn);
            xf1 = *reinterpret_cast<const float4*>(xn + 4);
        }

        const float* xr = &xs[wv][cur][tg2 * 16 * 20];   // this half's 16 rows

#pragma unroll 1
        for (int h = 0; h < 4; ++h) {                    // 4 ch-quads, ascending
#pragma unroll 8
            for (int tt = 0; tt < 16; ++tt) {
                const float4 xv =
                    *reinterpret_cast<const float4*>(xr + tt * 20 + h * 4);
                float a0 = accI[0][tt], a1 = accI[1][tt];
                a0 = fmaf(xv.x, wA[h].x, a0);
                a0 = fmaf(xv.y, wA[h].y, a0);
                a0 = fmaf(xv.z, wA[h].z, a0);
                a0 = fmaf(xv.w, wA[h].w, a0);
                a1 = fmaf(xv.x, wB[h].x, a1);
                a1 = fmaf(xv.y, wB[h].y, a1);
                a1 = fmaf(xv.z, wB[h].z, a1);
                a1 = fmaf(xv.w, wB[h].w, a1);
                accI[0][tt] = a0; accI[1][tt] = a1;
            }
        }

        if ((t & 15) == 15) {                            // flush every 256 ch
#pragma unroll
            for (int tt = 0; tt < 16; ++tt) {
                accO[0][tt] += accI[0][tt]; accI[0][tt] = 0.0f;
                accO[1][tt] += accI[1][tt]; accI[1][tt] = 0.0f;
            }
        }

        if (t + 1 < NTILE) {                             // commit to other buf
            float* wd = &xs[wv][cur ^ 1][srow * 20 + shalf * 8];
            *reinterpret_cast<float4*>(wd)     = xf0;
            *reinterpret_cast<float4*>(wd + 4) = xf1;
        }
        // NO barrier: tile is wave-private
    }

    // store partials: part[kq][tok][e]; consecutive e2 lanes -> coalesced
#pragma unroll
    for (int eh = 0; eh < 2; ++eh)
#pragma unroll
        for (int tt = 0; tt < 16; ++tt)
            part[((size_t)kq * T_TOTAL + wtok0 + tg2 * 16 + tt) * E_DIM
                 + eh * 32 + e2] = accO[eh][tt];
}

// ---- kernel 2: reduce 8 splits + sigmoid + top-8 + f/p partials ----
__global__ __launch_bounds__(256, 4)
void topk_kernel(const float* __restrict__ part,
                 const float* __restrict__ expert_bias,
                 float* __restrict__ out,
                 float* __restrict__ facc,
                 float* __restrict__ pacc) {
    const int lane = threadIdx.x & 63;
    const int wv   = threadIdx.x >> 6;
    const int tok0 = blockIdx.x * 64;

    __shared__ float slog[64][65];

    const int tt  = lane >> 2;
    const int s   = lane & 3;
    const int tl  = wv * 16 + tt;          // token-in-block
    const int tok = tok0 + tl;

    float4 sum4[4];
#pragma unroll
    for (int i = 0; i < 4; ++i) sum4[i] = make_float4(0.f, 0.f, 0.f, 0.f);
#pragma unroll
    for (int kq = 0; kq < NKQ; ++kq) {     // serial split sum (deterministic)
        const float4* pp = reinterpret_cast<const float4*>(
            part + ((size_t)kq * T_TOTAL + tok) * E_DIM + 16 * s);
#pragma unroll
        for (int i = 0; i < 4; ++i) {
            float4 v = pp[i];
            sum4[i].x += v.x; sum4[i].y += v.y;
            sum4[i].z += v.z; sum4[i].w += v.w;
        }
    }
#pragma unroll
    for (int i = 0; i < 4; ++i) {
        slog[tl][16 * s + 4 * i + 0] = sum4[i].x;
        slog[tl][16 * s + 4 * i + 1] = sum4[i].y;
        slog[tl][16 * s + 4 * i + 2] = sum4[i].z;
        slog[tl][16 * s + 4 * i + 3] = sum4[i].w;
    }
    __syncthreads();

    // ---- phase B: lane = expert; wave wv handles tokens wv*16 .. wv*16+15
    const float be = expert_bias[lane];
    const int   b  = tok0 / S_SEQ;         // uniform per block
    float f_local = 0.0f, p_local = 0.0f;

    for (int m = 0; m < 16; ++m) {
        const int tl2 = wv * 16 + m;
        const int tk  = tok0 + tl2;
        const float logit = slog[tl2][lane];
        const float sc = 1.0f / (1.0f + expf(-logit));   // sigmoid
        float ssum = sc;
#pragma unroll
        for (int off = 32; off >= 1; off >>= 1) ssum += __shfl_xor(ssum, off, 64);
        p_local += sc / (ssum + 1e-10f);

        // top-8 over biased logits (descending, lowest-index tie-break)
        float v = logit + be;
        float wsum = 0.0f, my_w = 0.0f;
        int   my_i = 0;
#pragma unroll
        for (int k = 0; k < K_TOP; ++k) {
            float rv = v;
            int   ri = lane;
#pragma unroll
            for (int off = 32; off >= 1; off >>= 1) {
                float ov = __shfl_xor(rv, off, 64);
                int   oi = __shfl_xor(ri, off, 64);
                if (ov > rv || (ov == rv && oi < ri)) { rv = ov; ri = oi; }
            }
            float wsc = __shfl(sc, ri, 64);   // winner's score (uniform)
            wsum += wsc;
            if (lane == k)  { my_i = ri; my_w = wsc; }
            if (lane == ri) { v = -INFINITY; f_local += 1.0f; }
        }
        if (lane < K_TOP) {
            out[(size_t)tk * K_TOP + lane] = (float)my_i;
            out[(size_t)T_TOTAL * K_TOP + (size_t)tk * K_TOP + lane] =
                my_w / (wsum + 1e-10f);
        }
    }

    atomicAdd(&facc[b * E_DIM + lane], f_local);
    atomicAdd(&pacc[b * E_DIM + lane], p_local);
}

// ---- tiny loss reduction: 4x64 f*p -> scalar ----
__global__ void loss_kernel(const float* __restrict__ facc,
                            const float* __restrict__ pacc,
                            float* __restrict__ out_loss) {
    const int tid = threadIdx.x;                 // 256 threads = B*E
    float f = facc[tid] * (1.0f / ((float)K_TOP * (float)S_SEQ));
    float p = pacc[tid] * (1.0f / (float)S_SEQ);
    float v = f * p;
#pragma unroll
    for (int off = 32; off >= 1; off >>= 1) v += __shfl_xor(v, off, 64);
    __shared__ float sred[4];
    if ((tid & 63) == 0) sred[tid >> 6] = v;
    __syncthreads();
    if (tid == 0) {
        float tot = sred[0] + sred[1] + sred[2] + sred[3];
        out_loss[0] = 0.001f * tot / (float)B_BATCH;
    }
}

extern "C" void kernel_launch(void* const* d_in, const int* in_sizes, int n_in,
                              void* d_out, int out_size, void* d_ws, size_t ws_size,
                              hipStream_t stream) {
    const float* x    = (const float*)d_in[0];   // [4,4096,4096] f32
    const float* w    = (const float*)d_in[1];   // [64,4096] f32
    const float* bias = (const float*)d_in[2];   // [64] f32
    float* out = (float*)d_out;                  // [131072 idx][131072 w][1 loss]

    float*  facc = (float*)d_ws;                 // 256 floats
    float*  pacc = facc + B_BATCH * E_DIM;       // 256 floats
    float4* wp3  = (float4*)((char*)d_ws + 4096);              // 1 MB packed W
    float*  part = (float*)((char*)d_ws + 4096 + (1 << 20));   // 32 MB partials

    // zero the f/p accumulators every call (atomics accumulate)
    hipMemsetAsync(d_ws, 0, 2048, stream);

    pack_w_kernel<<<256, 256, 0, stream>>>(w, wp3);

    gemv_kernel<<<128 * NKQ, 256, 0, stream>>>(x, wp3, part);

    topk_kernel<<<T_TOTAL / 64, 256, 0, stream>>>(part, bias, out, facc, pacc);

    loss_kernel<<<1, 256, 0, stream>>>(facc, pacc, out + 2 * (size_t)T_TOTAL * K_TOP);
}